// Round 6
// baseline (422.035 us; speedup 1.0000x reference)
//
#include <hip/hip_runtime.h>
#include <hip/hip_bf16.h>

#define DIM 64
#define RELS 32
#define SCAN_B 512
#define TILE_V 64

// ---- Precompute M[v][r] = dot(ent[v], rel[r]) * 0.125 as bf16 (12.8 MB, L2-resident) ----
// Both operands in LDS: ent tile coalesced-staged (broadcast reads), rel transposed SoA
// (bank-conflict-free: word addr d4*32+r -> bank r). Low VGPR -> high occupancy.
__global__ __launch_bounds__(256) void build_M(
    const float* __restrict__ ent, const float* __restrict__ rel,
    __hip_bfloat16* __restrict__ M, int nE) {
    __shared__ float4 entL[TILE_V * 16];    // 16 KB
    __shared__ float relT[4][16][32];       // 8 KB: [component][d4][r] -> bank r
    int tx = threadIdx.x;
    int r  = tx & 31;                       // relation id
    int vg = tx >> 5;                       // vertex group 0..7
    int base = blockIdx.x * TILE_V;

    // stage rel transposed (one-time 32-way write scatter, negligible)
    const float4* rel4 = (const float4*)rel;
    #pragma unroll
    for (int k = 0; k < 2; k++) {
        int idx = tx + k * 256;             // 0..511 = rr*16 + d4
        float4 v = rel4[idx];
        int rr = idx >> 4, d4 = idx & 15;
        relT[0][d4][rr] = v.x; relT[1][d4][rr] = v.y;
        relT[2][d4][rr] = v.z; relT[3][d4][rr] = v.w;
    }

    // stage 64-row ent tile, fully coalesced
    const float4* ent4 = (const float4*)ent;
    #pragma unroll
    for (int k = 0; k < 4; k++) {
        int idx = tx + k * 256;             // 0..1023
        int v = base + (idx >> 4);
        entL[idx] = (v < nE) ? ent4[(size_t)v * 16 + (idx & 15)]
                             : make_float4(0.f, 0.f, 0.f, 0.f);
    }
    __syncthreads();

    // 8 vertices per thread; rel slice from LDS (conflict-free), ent broadcast
    float acc[8] = {0.f, 0.f, 0.f, 0.f, 0.f, 0.f, 0.f, 0.f};
    for (int d4 = 0; d4 < 16; d4++) {
        float rx = relT[0][d4][r], ry = relT[1][d4][r];
        float rz = relT[2][d4][r], rw = relT[3][d4][r];
        #pragma unroll
        for (int i = 0; i < 8; i++) {
            float4 a = entL[(vg * 8 + i) * 16 + d4];
            acc[i] = fmaf(a.x, rx, fmaf(a.y, ry, fmaf(a.z, rz, fmaf(a.w, rw, acc[i]))));
        }
    }
    #pragma unroll
    for (int i = 0; i < 8; i++) {
        int v = base + vg * 8 + i;
        if (v < nE) M[(size_t)v * RELS + r] = __float2bfloat16(acc[i] * 0.125f);
    }
}

// ---- Degree histogram + stable ranks (no embeddings needed) ----
__global__ __launch_bounds__(256) void deg_count(
    const int* __restrict__ head, const int* __restrict__ uidx,
    unsigned int* __restrict__ deg,
    unsigned int* __restrict__ rank_e, unsigned int* __restrict__ rank_i,
    int E, int I, int nE) {
    int t = blockIdx.x * blockDim.x + threadIdx.x;
    if (t < E) rank_e[t] = atomicAdd(&deg[head[t]], 1u);
    else if (t < E + I) { int e = t - E; rank_i[e] = atomicAdd(&deg[nE + uidx[e]], 1u); }
}

// ---- Scan step 1 ----
__global__ __launch_bounds__(SCAN_B) void scan_partial(
    const unsigned int* __restrict__ deg, unsigned int* __restrict__ part, int n) {
    __shared__ unsigned int lds[SCAN_B];
    int i = blockIdx.x * SCAN_B + threadIdx.x;
    lds[threadIdx.x] = (i < n) ? deg[i] : 0u;
    __syncthreads();
    for (int off = SCAN_B >> 1; off > 0; off >>= 1) {
        if (threadIdx.x < off) lds[threadIdx.x] += lds[threadIdx.x + off];
        __syncthreads();
    }
    if (threadIdx.x == 0) part[blockIdx.x] = lds[0];
}

// ---- Scan step 2 ----
__global__ __launch_bounds__(1024) void scan_block(unsigned int* __restrict__ part, int nb) {
    __shared__ unsigned int lds[1024];
    int t = threadIdx.x;
    unsigned int v = (t < nb) ? part[t] : 0u;
    lds[t] = v;
    __syncthreads();
    for (int off = 1; off < 1024; off <<= 1) {
        unsigned int x = (t >= off) ? lds[t - off] : 0u;
        __syncthreads();
        lds[t] += x;
        __syncthreads();
    }
    if (t < nb) part[t] = lds[t] - v;
}

// ---- Scan step 3 ----
__global__ __launch_bounds__(SCAN_B) void scan_final(
    const unsigned int* __restrict__ deg, const unsigned int* __restrict__ part,
    unsigned int* __restrict__ offs, int n) {
    __shared__ unsigned int lds[SCAN_B];
    int t = threadIdx.x;
    int i = blockIdx.x * SCAN_B + t;
    unsigned int v = (i < n) ? deg[i] : 0u;
    lds[t] = v;
    __syncthreads();
    for (int off = 1; off < SCAN_B; off <<= 1) {
        unsigned int x = (t >= off) ? lds[t - off] : 0u;
        __syncthreads();
        lds[t] += x;
        __syncthreads();
    }
    if (i < n) offs[i] = part[blockIdx.x] + lds[t] - v;
}

// ---- Fused score (table lookup) + atomic-free scatter of CSR payloads ----
__global__ __launch_bounds__(256) void score_scatter(
    const __hip_bfloat16* __restrict__ M,
    const int* __restrict__ head, const int* __restrict__ tail, const int* __restrict__ etype,
    const int* __restrict__ uidx, const int* __restrict__ iidx, const int* __restrict__ ttype,
    const unsigned int* __restrict__ rank_e, const unsigned int* __restrict__ rank_i,
    const unsigned int* __restrict__ offs,
    unsigned long long* __restrict__ pay, unsigned int* __restrict__ payu,
    int E, int I, int nE) {
    int t = blockIdx.x * blockDim.x + threadIdx.x;
    if (t < E) {
        int tl = tail[t];
        float sc = __bfloat162float(M[(size_t)tl * RELS + (etype[t] - 1)]);
        unsigned int p = offs[head[t]] + rank_e[t];
        unsigned long long v = ((unsigned long long)(unsigned int)__float_as_int(sc) << 32)
                             | (unsigned int)tl;
        __builtin_nontemporal_store(v, &pay[p]);
    } else if (t < E + I) {
        int e = t - E;
        unsigned int p = offs[nE + uidx[e]] + rank_i[e] - (unsigned)E;
        unsigned int v = (unsigned int)iidx[e] | ((unsigned int)ttype[e] << 27);
        __builtin_nontemporal_store(v, &payu[p]);
    }
}

// ---- Entity: online-softmax weighted gather-accumulate, 2-deep prefetch ----
__global__ __launch_bounds__(256) void agg_entity(
    const float* __restrict__ emb, const unsigned long long* __restrict__ pay,
    const unsigned int* __restrict__ deg, const unsigned int* __restrict__ offs,
    float2* __restrict__ msum, float* __restrict__ agg, int nSeg) {
    int t = blockIdx.x * blockDim.x + threadIdx.x;
    int h = t >> 4, l = t & 15;
    if (h >= nSeg) return;
    unsigned int d = deg[h];
    float m = -3.0e38f, s = 0.f, inv = 0.f;
    float4 acc = make_float4(0.f, 0.f, 0.f, 0.f);
    if (d) {
        unsigned int off = offs[h];
        unsigned long long v0 = pay[off];
        float4 a0 = ((const float4*)(emb + (size_t)(unsigned int)(v0 & 0xffffffffu) * DIM))[l];
        for (unsigned int j = 0; j < d; j++) {
            unsigned long long v1 = v0; float4 a1 = a0;
            if (j + 1 < d) {
                v1 = pay[off + j + 1];
                a1 = ((const float4*)(emb + (size_t)(unsigned int)(v1 & 0xffffffffu) * DIM))[l];
            }
            float sc = __int_as_float((int)(v0 >> 32));
            float mn = fmaxf(m, sc);
            float scale = __expf(m - mn);
            float w = __expf(sc - mn);
            s = s * scale + w;
            acc.x = acc.x * scale + w * a0.x;
            acc.y = acc.y * scale + w * a0.y;
            acc.z = acc.z * scale + w * a0.z;
            acc.w = acc.w * scale + w * a0.w;
            m = mn; v0 = v1; a0 = a1;
        }
        inv = 1.f / s;
    }
    if (l == 0) msum[h] = make_float2(m, inv);
    acc.x *= inv; acc.y *= inv; acc.z *= inv; acc.w *= inv;
    ((float4*)(agg + (size_t)h * DIM))[l] = acc;
}

// ---- User: fused score + online softmax + aggregate (usr row loaded once) ----
__global__ __launch_bounds__(256) void user_fused(
    const float* __restrict__ ent, const float* __restrict__ usr,
    const float* __restrict__ itc, const unsigned int* __restrict__ payu,
    const unsigned int* __restrict__ deg, const unsigned int* __restrict__ offs,
    int nE, int E, float* __restrict__ patt, float2* __restrict__ msum,
    float* __restrict__ agg, int nU) {
    __shared__ float4 itcL[8][16];
    int tx = threadIdx.x;
    if (tx < 128) itcL[tx >> 4][tx & 15] = ((const float4*)itc)[tx];
    __syncthreads();
    int t = blockIdx.x * blockDim.x + tx;
    int h = t >> 4, l = t & 15;
    if (h >= nU) return;
    unsigned int d = deg[nE + h];
    float m = -3.0e38f, s = 0.f, inv = 0.f;
    float4 acc = make_float4(0.f, 0.f, 0.f, 0.f);
    float4 ur = ((const float4*)(usr + (size_t)h * DIM))[l];
    if (d) {
        unsigned int off = offs[nE + h] - (unsigned)E;
        unsigned int v0 = payu[off];
        float4 a0 = ((const float4*)(ent + (size_t)(v0 & 0x7ffffffu) * DIM))[l];
        for (unsigned int j = 0; j < d; j++) {
            unsigned int v1 = v0; float4 a1 = a0;
            if (j + 1 < d) {
                v1 = payu[off + j + 1];
                a1 = ((const float4*)(ent + (size_t)(v1 & 0x7ffffffu) * DIM))[l];
            }
            float4 c = itcL[v0 >> 27][l];
            float p = a0.x * ur.x * c.x + a0.y * ur.y * c.y
                    + a0.z * ur.z * c.z + a0.w * ur.w * c.w;
            p += __shfl_xor(p, 1);
            p += __shfl_xor(p, 2);
            p += __shfl_xor(p, 4);
            p += __shfl_xor(p, 8);
            if (l == 0) patt[off + j] = p;
            float mn = fmaxf(m, p);
            float scale = __expf(m - mn);
            float w = __expf(p - mn);
            s = s * scale + w;
            acc.x = acc.x * scale + w * a0.x;
            acc.y = acc.y * scale + w * a0.y;
            acc.z = acc.z * scale + w * a0.z;
            acc.w = acc.w * scale + w * a0.w;
            m = mn; v0 = v1; a0 = a1;
        }
        inv = 1.f / s;
    }
    if (l == 0) msum[nE + h] = make_float2(m, inv);
    acc.x *= inv; acc.y *= inv; acc.z *= inv; acc.w *= inv;
    ((float4*)(agg + (size_t)h * DIM))[l] = acc;
}

// ---- Epilogue: coalesced per-edge weight writes ----
__global__ __launch_bounds__(256) void wout(
    const int* __restrict__ head, const int* __restrict__ uidx,
    const unsigned long long* __restrict__ pay, const float* __restrict__ patt,
    const unsigned int* __restrict__ rank_e, const unsigned int* __restrict__ rank_i,
    const unsigned int* __restrict__ offs, const float2* __restrict__ msum,
    float* __restrict__ w1, float* __restrict__ attw, int E, int I, int nE) {
    int t = blockIdx.x * blockDim.x + threadIdx.x;
    if (t < E) {
        int hd = head[t];
        float2 mi = msum[hd];
        unsigned long long v = pay[offs[hd] + rank_e[t]];
        w1[t] = __expf(__int_as_float((int)(v >> 32)) - mi.x) * mi.y;
    } else if (t < E + I) {
        int e = t - E; int u = uidx[e];
        float2 mi = msum[nE + u];
        float sc = patt[offs[nE + u] - (unsigned)E + rank_i[e]];
        attw[e] = __expf(sc - mi.x) * mi.y;
    }
}

extern "C" void kernel_launch(void* const* d_in, const int* in_sizes, int n_in,
                              void* d_out, int out_size, void* d_ws, size_t ws_size,
                              hipStream_t stream) {
    const float* ent  = (const float*)d_in[0];
    const float* usr  = (const float*)d_in[1];
    const float* itc  = (const float*)d_in[2];
    const float* rel  = (const float*)d_in[3];
    const int* eidx   = (const int*)d_in[4];
    const int* etype  = (const int*)d_in[5];
    const int* uidx   = (const int*)d_in[6];
    const int* iidx   = (const int*)d_in[7];
    const int* ttype  = (const int*)d_in[8];

    const int E  = in_sizes[4] / 2;
    const int I  = in_sizes[6];
    const int nE = in_sizes[0] / DIM;
    const int nU = in_sizes[1] / DIM;
    const int* head = eidx;
    const int* tail = eidx + E;
    const int NSEG = nE + nU;
    const int NB = (NSEG + SCAN_B - 1) / SCAN_B;   // <= 1024

    float* out_entity = (float*)d_out;
    float* out_user   = out_entity + (size_t)nE * DIM;
    float* out_attw   = out_user + (size_t)nU * DIM;
    float* out_w1     = out_attw + I;

    // workspace layout (word offsets even where 8B alignment needed)
    unsigned int* deg     = (unsigned int*)d_ws;            // NSEG
    unsigned int* offs    = deg + NSEG;                     // NSEG
    unsigned int* part    = offs + NSEG;                    // 1024
    unsigned int* rank_e  = part + 1024;                    // E
    unsigned int* rank_i  = rank_e + E;                     // I
    unsigned long long* pay = (unsigned long long*)(rank_i + I);  // E u64
    unsigned int* payu    = (unsigned int*)(pay + E);       // I
    // M region (nE*RELS bf16), dead after score_scatter; msum/patt alias it.
    __hip_bfloat16* M = (__hip_bfloat16*)(payu + I);
    float2* msum = (float2*)(payu + I);                     // NSEG float2
    float* patt  = (float*)(msum + NSEG);                   // I floats

    hipMemsetAsync(deg, 0, (size_t)NSEG * sizeof(unsigned int), stream);

    const int T = 256;
    dim3 gM((unsigned)((nE + TILE_V - 1) / TILE_V));
    dim3 gEI((unsigned)((E + I + T - 1) / T));
    dim3 gAE((unsigned)(((size_t)nE * 16 + T - 1) / T));
    dim3 gAU((unsigned)(((size_t)nU * 16 + T - 1) / T));

    build_M<<<gM, T, 0, stream>>>(ent, rel, M, nE);
    deg_count<<<gEI, T, 0, stream>>>(head, uidx, deg, rank_e, rank_i, E, I, nE);

    scan_partial<<<dim3((unsigned)NB), SCAN_B, 0, stream>>>(deg, part, NSEG);
    scan_block<<<dim3(1), 1024, 0, stream>>>(part, NB);
    scan_final<<<dim3((unsigned)NB), SCAN_B, 0, stream>>>(deg, part, offs, NSEG);

    score_scatter<<<gEI, T, 0, stream>>>(M, head, tail, etype, uidx, iidx, ttype,
                                         rank_e, rank_i, offs, pay, payu, E, I, nE);

    agg_entity<<<gAE, T, 0, stream>>>(ent, pay, deg, offs, msum, out_entity, nE);
    user_fused<<<gAU, T, 0, stream>>>(ent, usr, itc, payu, deg, offs, nE, E,
                                      patt, msum, out_user, nU);

    wout<<<gEI, T, 0, stream>>>(head, uidx, pay, patt, rank_e, rank_i, offs, msum,
                                out_w1, out_attw, E, I, nE);
}

// Round 7
// 335.637 us; speedup vs baseline: 1.2574x; 1.2574x over previous
//
#include <hip/hip_runtime.h>
#include <hip/hip_bf16.h>

#define DIM 64
#define RELS 32
#define SCAN_B 512
#define TILE_V 64

// ---- Precompute M[v][r] = dot(ent[v], rel[r]) * 0.125 as bf16 (12.8 MB) ----
// Register-blocked 4v x 2r per thread; ent tile padded 17-float4 rows (2-way
// bank = free), rel as component planes [4][16][33] (2-way = free).
// unroll 2 + launch_bounds(256,4): bounded live range, no spills.
__global__ __launch_bounds__(256, 4) void build_M(
    const float* __restrict__ ent, const float* __restrict__ rel,
    __hip_bfloat16* __restrict__ M, int nE) {
    __shared__ float4 entL[TILE_V * 17];    // 64 rows x (16+1 pad) float4 = 17.4 KB
    __shared__ float relS[4][16][33];       // [comp][d4][r], pad 33 = 8.4 KB
    int tx = threadIdx.x;
    int vg = tx >> 4;                       // vertex group 0..15 (4 vertices each)
    int rg = tx & 15;                       // relation group 0..15 (2 relations each)
    int base = blockIdx.x * TILE_V;

    // stage rel as component planes; consecutive lanes -> d4 consecutive (stride 33 w: ~free)
    const float4* rel4 = (const float4*)rel;
    #pragma unroll
    for (int k = 0; k < 2; k++) {
        int idx = tx + k * 256;             // 0..511 = r*16 + d4
        float4 v = rel4[idx];
        int r = idx >> 4, d4 = idx & 15;
        relS[0][d4][r] = v.x; relS[1][d4][r] = v.y;
        relS[2][d4][r] = v.z; relS[3][d4][r] = v.w;
    }

    // stage 64-row ent tile, coalesced reads, padded rows
    const float4* ent4 = (const float4*)ent;
    #pragma unroll
    for (int k = 0; k < 4; k++) {
        int idx = tx + k * 256;             // 0..1023
        int row = idx >> 4, col = idx & 15;
        int v = base + row;
        entL[row * 17 + col] = (v < nE) ? ent4[(size_t)v * 16 + col]
                                        : make_float4(0.f, 0.f, 0.f, 0.f);
    }
    __syncthreads();

    float acc[4][2] = {{0.f,0.f},{0.f,0.f},{0.f,0.f},{0.f,0.f}};
    int r0 = rg * 2;
    #pragma unroll 2
    for (int d4 = 0; d4 < 16; d4++) {
        float4 a0 = entL[(vg * 4 + 0) * 17 + d4];
        float4 a1 = entL[(vg * 4 + 1) * 17 + d4];
        float4 a2 = entL[(vg * 4 + 2) * 17 + d4];
        float4 a3 = entL[(vg * 4 + 3) * 17 + d4];
        float bx0 = relS[0][d4][r0],     by0 = relS[1][d4][r0];
        float bz0 = relS[2][d4][r0],     bw0 = relS[3][d4][r0];
        float bx1 = relS[0][d4][r0 + 1], by1 = relS[1][d4][r0 + 1];
        float bz1 = relS[2][d4][r0 + 1], bw1 = relS[3][d4][r0 + 1];
        acc[0][0] = fmaf(a0.x,bx0, fmaf(a0.y,by0, fmaf(a0.z,bz0, fmaf(a0.w,bw0, acc[0][0]))));
        acc[1][0] = fmaf(a1.x,bx0, fmaf(a1.y,by0, fmaf(a1.z,bz0, fmaf(a1.w,bw0, acc[1][0]))));
        acc[2][0] = fmaf(a2.x,bx0, fmaf(a2.y,by0, fmaf(a2.z,bz0, fmaf(a2.w,bw0, acc[2][0]))));
        acc[3][0] = fmaf(a3.x,bx0, fmaf(a3.y,by0, fmaf(a3.z,bz0, fmaf(a3.w,bw0, acc[3][0]))));
        acc[0][1] = fmaf(a0.x,bx1, fmaf(a0.y,by1, fmaf(a0.z,bz1, fmaf(a0.w,bw1, acc[0][1]))));
        acc[1][1] = fmaf(a1.x,bx1, fmaf(a1.y,by1, fmaf(a1.z,bz1, fmaf(a1.w,bw1, acc[1][1]))));
        acc[2][1] = fmaf(a2.x,bx1, fmaf(a2.y,by1, fmaf(a2.z,bz1, fmaf(a2.w,bw1, acc[2][1]))));
        acc[3][1] = fmaf(a3.x,bx1, fmaf(a3.y,by1, fmaf(a3.z,bz1, fmaf(a3.w,bw1, acc[3][1]))));
    }

    // packed bf16x2 stores: u32 slot rg of each row -> coalesced
    __hip_bfloat162* M2 = (__hip_bfloat162*)M;
    #pragma unroll
    for (int i = 0; i < 4; i++) {
        int v = base + vg * 4 + i;
        if (v < nE) {
            __hip_bfloat16 h0 = __float2bfloat16(acc[i][0] * 0.125f);
            __hip_bfloat16 h1 = __float2bfloat16(acc[i][1] * 0.125f);
            M2[(size_t)v * 16 + rg] = __halves2bfloat162(h0, h1);
        }
    }
}

// ---- Degree histogram + stable ranks (no embeddings needed) ----
__global__ __launch_bounds__(256) void deg_count(
    const int* __restrict__ head, const int* __restrict__ uidx,
    unsigned int* __restrict__ deg,
    unsigned int* __restrict__ rank_e, unsigned int* __restrict__ rank_i,
    int E, int I, int nE) {
    int t = blockIdx.x * blockDim.x + threadIdx.x;
    if (t < E) rank_e[t] = atomicAdd(&deg[head[t]], 1u);
    else if (t < E + I) { int e = t - E; rank_i[e] = atomicAdd(&deg[nE + uidx[e]], 1u); }
}

// ---- Scan step 1 ----
__global__ __launch_bounds__(SCAN_B) void scan_partial(
    const unsigned int* __restrict__ deg, unsigned int* __restrict__ part, int n) {
    __shared__ unsigned int lds[SCAN_B];
    int i = blockIdx.x * SCAN_B + threadIdx.x;
    lds[threadIdx.x] = (i < n) ? deg[i] : 0u;
    __syncthreads();
    for (int off = SCAN_B >> 1; off > 0; off >>= 1) {
        if (threadIdx.x < off) lds[threadIdx.x] += lds[threadIdx.x + off];
        __syncthreads();
    }
    if (threadIdx.x == 0) part[blockIdx.x] = lds[0];
}

// ---- Scan step 2 ----
__global__ __launch_bounds__(1024) void scan_block(unsigned int* __restrict__ part, int nb) {
    __shared__ unsigned int lds[1024];
    int t = threadIdx.x;
    unsigned int v = (t < nb) ? part[t] : 0u;
    lds[t] = v;
    __syncthreads();
    for (int off = 1; off < 1024; off <<= 1) {
        unsigned int x = (t >= off) ? lds[t - off] : 0u;
        __syncthreads();
        lds[t] += x;
        __syncthreads();
    }
    if (t < nb) part[t] = lds[t] - v;
}

// ---- Scan step 3 ----
__global__ __launch_bounds__(SCAN_B) void scan_final(
    const unsigned int* __restrict__ deg, const unsigned int* __restrict__ part,
    unsigned int* __restrict__ offs, int n) {
    __shared__ unsigned int lds[SCAN_B];
    int t = threadIdx.x;
    int i = blockIdx.x * SCAN_B + t;
    unsigned int v = (i < n) ? deg[i] : 0u;
    lds[t] = v;
    __syncthreads();
    for (int off = 1; off < SCAN_B; off <<= 1) {
        unsigned int x = (t >= off) ? lds[t - off] : 0u;
        __syncthreads();
        lds[t] += x;
        __syncthreads();
    }
    if (i < n) offs[i] = part[blockIdx.x] + lds[t] - v;
}

// ---- Fused score (table lookup) + atomic-free scatter of CSR payloads ----
__global__ __launch_bounds__(256) void score_scatter(
    const __hip_bfloat16* __restrict__ M,
    const int* __restrict__ head, const int* __restrict__ tail, const int* __restrict__ etype,
    const int* __restrict__ uidx, const int* __restrict__ iidx, const int* __restrict__ ttype,
    const unsigned int* __restrict__ rank_e, const unsigned int* __restrict__ rank_i,
    const unsigned int* __restrict__ offs,
    unsigned long long* __restrict__ pay, unsigned int* __restrict__ payu,
    int E, int I, int nE) {
    int t = blockIdx.x * blockDim.x + threadIdx.x;
    if (t < E) {
        int tl = tail[t];
        float sc = __bfloat162float(M[(size_t)tl * RELS + (etype[t] - 1)]);
        unsigned int p = offs[head[t]] + rank_e[t];
        unsigned long long v = ((unsigned long long)(unsigned int)__float_as_int(sc) << 32)
                             | (unsigned int)tl;
        __builtin_nontemporal_store(v, &pay[p]);
    } else if (t < E + I) {
        int e = t - E;
        unsigned int p = offs[nE + uidx[e]] + rank_i[e] - (unsigned)E;
        unsigned int v = (unsigned int)iidx[e] | ((unsigned int)ttype[e] << 27);
        __builtin_nontemporal_store(v, &payu[p]);
    }
}

// ---- Entity: online-softmax weighted gather-accumulate, 2-deep prefetch ----
__global__ __launch_bounds__(256) void agg_entity(
    const float* __restrict__ emb, const unsigned long long* __restrict__ pay,
    const unsigned int* __restrict__ deg, const unsigned int* __restrict__ offs,
    float2* __restrict__ msum, float* __restrict__ agg, int nSeg) {
    int t = blockIdx.x * blockDim.x + threadIdx.x;
    int h = t >> 4, l = t & 15;
    if (h >= nSeg) return;
    unsigned int d = deg[h];
    float m = -3.0e38f, s = 0.f, inv = 0.f;
    float4 acc = make_float4(0.f, 0.f, 0.f, 0.f);
    if (d) {
        unsigned int off = offs[h];
        unsigned long long v0 = pay[off];
        float4 a0 = ((const float4*)(emb + (size_t)(unsigned int)(v0 & 0xffffffffu) * DIM))[l];
        for (unsigned int j = 0; j < d; j++) {
            unsigned long long v1 = v0; float4 a1 = a0;
            if (j + 1 < d) {
                v1 = pay[off + j + 1];
                a1 = ((const float4*)(emb + (size_t)(unsigned int)(v1 & 0xffffffffu) * DIM))[l];
            }
            float sc = __int_as_float((int)(v0 >> 32));
            float mn = fmaxf(m, sc);
            float scale = __expf(m - mn);
            float w = __expf(sc - mn);
            s = s * scale + w;
            acc.x = acc.x * scale + w * a0.x;
            acc.y = acc.y * scale + w * a0.y;
            acc.z = acc.z * scale + w * a0.z;
            acc.w = acc.w * scale + w * a0.w;
            m = mn; v0 = v1; a0 = a1;
        }
        inv = 1.f / s;
    }
    if (l == 0) msum[h] = make_float2(m, inv);
    acc.x *= inv; acc.y *= inv; acc.z *= inv; acc.w *= inv;
    ((float4*)(agg + (size_t)h * DIM))[l] = acc;
}

// ---- User: fused score + online softmax + aggregate (usr row loaded once) ----
__global__ __launch_bounds__(256) void user_fused(
    const float* __restrict__ ent, const float* __restrict__ usr,
    const float* __restrict__ itc, const unsigned int* __restrict__ payu,
    const unsigned int* __restrict__ deg, const unsigned int* __restrict__ offs,
    int nE, int E, float* __restrict__ patt, float2* __restrict__ msum,
    float* __restrict__ agg, int nU) {
    __shared__ float4 itcL[8][16];
    int tx = threadIdx.x;
    if (tx < 128) itcL[tx >> 4][tx & 15] = ((const float4*)itc)[tx];
    __syncthreads();
    int t = blockIdx.x * blockDim.x + tx;
    int h = t >> 4, l = t & 15;
    if (h >= nU) return;
    unsigned int d = deg[nE + h];
    float m = -3.0e38f, s = 0.f, inv = 0.f;
    float4 acc = make_float4(0.f, 0.f, 0.f, 0.f);
    float4 ur = ((const float4*)(usr + (size_t)h * DIM))[l];
    if (d) {
        unsigned int off = offs[nE + h] - (unsigned)E;
        unsigned int v0 = payu[off];
        float4 a0 = ((const float4*)(ent + (size_t)(v0 & 0x7ffffffu) * DIM))[l];
        for (unsigned int j = 0; j < d; j++) {
            unsigned int v1 = v0; float4 a1 = a0;
            if (j + 1 < d) {
                v1 = payu[off + j + 1];
                a1 = ((const float4*)(ent + (size_t)(v1 & 0x7ffffffu) * DIM))[l];
            }
            float4 c = itcL[v0 >> 27][l];
            float p = a0.x * ur.x * c.x + a0.y * ur.y * c.y
                    + a0.z * ur.z * c.z + a0.w * ur.w * c.w;
            p += __shfl_xor(p, 1);
            p += __shfl_xor(p, 2);
            p += __shfl_xor(p, 4);
            p += __shfl_xor(p, 8);
            if (l == 0) patt[off + j] = p;
            float mn = fmaxf(m, p);
            float scale = __expf(m - mn);
            float w = __expf(p - mn);
            s = s * scale + w;
            acc.x = acc.x * scale + w * a0.x;
            acc.y = acc.y * scale + w * a0.y;
            acc.z = acc.z * scale + w * a0.z;
            acc.w = acc.w * scale + w * a0.w;
            m = mn; v0 = v1; a0 = a1;
        }
        inv = 1.f / s;
    }
    if (l == 0) msum[nE + h] = make_float2(m, inv);
    acc.x *= inv; acc.y *= inv; acc.z *= inv; acc.w *= inv;
    ((float4*)(agg + (size_t)h * DIM))[l] = acc;
}

// ---- Epilogue: coalesced per-edge weight writes ----
__global__ __launch_bounds__(256) void wout(
    const int* __restrict__ head, const int* __restrict__ uidx,
    const unsigned long long* __restrict__ pay, const float* __restrict__ patt,
    const unsigned int* __restrict__ rank_e, const unsigned int* __restrict__ rank_i,
    const unsigned int* __restrict__ offs, const float2* __restrict__ msum,
    float* __restrict__ w1, float* __restrict__ attw, int E, int I, int nE) {
    int t = blockIdx.x * blockDim.x + threadIdx.x;
    if (t < E) {
        int hd = head[t];
        float2 mi = msum[hd];
        unsigned long long v = pay[offs[hd] + rank_e[t]];
        w1[t] = __expf(__int_as_float((int)(v >> 32)) - mi.x) * mi.y;
    } else if (t < E + I) {
        int e = t - E; int u = uidx[e];
        float2 mi = msum[nE + u];
        float sc = patt[offs[nE + u] - (unsigned)E + rank_i[e]];
        attw[e] = __expf(sc - mi.x) * mi.y;
    }
}

extern "C" void kernel_launch(void* const* d_in, const int* in_sizes, int n_in,
                              void* d_out, int out_size, void* d_ws, size_t ws_size,
                              hipStream_t stream) {
    const float* ent  = (const float*)d_in[0];
    const float* usr  = (const float*)d_in[1];
    const float* itc  = (const float*)d_in[2];
    const float* rel  = (const float*)d_in[3];
    const int* eidx   = (const int*)d_in[4];
    const int* etype  = (const int*)d_in[5];
    const int* uidx   = (const int*)d_in[6];
    const int* iidx   = (const int*)d_in[7];
    const int* ttype  = (const int*)d_in[8];

    const int E  = in_sizes[4] / 2;
    const int I  = in_sizes[6];
    const int nE = in_sizes[0] / DIM;
    const int nU = in_sizes[1] / DIM;
    const int* head = eidx;
    const int* tail = eidx + E;
    const int NSEG = nE + nU;
    const int NB = (NSEG + SCAN_B - 1) / SCAN_B;   // <= 1024

    float* out_entity = (float*)d_out;
    float* out_user   = out_entity + (size_t)nE * DIM;
    float* out_attw   = out_user + (size_t)nU * DIM;
    float* out_w1     = out_attw + I;

    // workspace layout (word offsets even where 8B alignment needed)
    unsigned int* deg     = (unsigned int*)d_ws;            // NSEG
    unsigned int* offs    = deg + NSEG;                     // NSEG
    unsigned int* part    = offs + NSEG;                    // 1024
    unsigned int* rank_e  = part + 1024;                    // E
    unsigned int* rank_i  = rank_e + E;                     // I
    unsigned long long* pay = (unsigned long long*)(rank_i + I);  // E u64
    unsigned int* payu    = (unsigned int*)(pay + E);       // I
    // M region (nE*RELS bf16), dead after score_scatter; msum/patt alias it.
    __hip_bfloat16* M = (__hip_bfloat16*)(payu + I);
    float2* msum = (float2*)(payu + I);                     // NSEG float2
    float* patt  = (float*)(msum + NSEG);                   // I floats

    hipMemsetAsync(deg, 0, (size_t)NSEG * sizeof(unsigned int), stream);

    const int T = 256;
    dim3 gM((unsigned)((nE + TILE_V - 1) / TILE_V));
    dim3 gEI((unsigned)((E + I + T - 1) / T));
    dim3 gAE((unsigned)(((size_t)nE * 16 + T - 1) / T));
    dim3 gAU((unsigned)(((size_t)nU * 16 + T - 1) / T));

    build_M<<<gM, T, 0, stream>>>(ent, rel, M, nE);
    deg_count<<<gEI, T, 0, stream>>>(head, uidx, deg, rank_e, rank_i, E, I, nE);

    scan_partial<<<dim3((unsigned)NB), SCAN_B, 0, stream>>>(deg, part, NSEG);
    scan_block<<<dim3(1), 1024, 0, stream>>>(part, NB);
    scan_final<<<dim3((unsigned)NB), SCAN_B, 0, stream>>>(deg, part, offs, NSEG);

    score_scatter<<<gEI, T, 0, stream>>>(M, head, tail, etype, uidx, iidx, ttype,
                                         rank_e, rank_i, offs, pay, payu, E, I, nE);

    agg_entity<<<gAE, T, 0, stream>>>(ent, pay, deg, offs, msum, out_entity, nE);
    user_fused<<<gAU, T, 0, stream>>>(ent, usr, itc, payu, deg, offs, nE, E,
                                      patt, msum, out_user, nU);

    wout<<<gEI, T, 0, stream>>>(head, uidx, pay, patt, rank_e, rank_i, offs, msum,
                                out_w1, out_attw, E, I, nE);
}

// Round 8
// 332.892 us; speedup vs baseline: 1.2678x; 1.0082x over previous
//
#include <hip/hip_runtime.h>
#include <hip/hip_bf16.h>

#define DIM 64
#define RELS 32
#define SCAN_B 512
#define TILE_V 64

// ============ Kernel A: build_M blocks + packed-degree-count blocks ============
// build_M: M[v][r] = dot(ent[v], rel[r])/8 as bf16. Register-blocked 4v x 2r.
// deg: degP packs 4 u8 counters per u32; atomicAdd(1<<8*sub) returns rank byte.
__global__ __launch_bounds__(256, 4) void buildM_deg(
    const float* __restrict__ ent, const float* __restrict__ rel,
    __hip_bfloat16* __restrict__ M,
    const int* __restrict__ head, const int* __restrict__ uidx,
    unsigned int* __restrict__ degP,
    unsigned char* __restrict__ rank_e, unsigned char* __restrict__ rank_i,
    int nE, int E, int I, int gM) {
    __shared__ float4 entL[TILE_V * 17];
    __shared__ float relS[4][16][33];
    int tx = threadIdx.x;
    int bid = blockIdx.x;

    if (bid >= gM) {
        // ---- degree/rank blocks ----
        int t = (bid - gM) * 256 + tx;
        if (t < E) {
            int s = head[t];
            unsigned int old = atomicAdd(&degP[s >> 2], 1u << (8 * (s & 3)));
            rank_e[t] = (unsigned char)((old >> (8 * (s & 3))) & 0xFFu);
        } else if (t < E + I) {
            int e = t - E;
            int s = nE + uidx[e];
            unsigned int old = atomicAdd(&degP[s >> 2], 1u << (8 * (s & 3)));
            rank_i[e] = (unsigned char)((old >> (8 * (s & 3))) & 0xFFu);
        }
        return;
    }

    // ---- build_M blocks ----
    int vg = tx >> 4, rg = tx & 15;
    int base = bid * TILE_V;
    const float4* rel4 = (const float4*)rel;
    #pragma unroll
    for (int k = 0; k < 2; k++) {
        int idx = tx + k * 256;
        float4 v = rel4[idx];
        int r = idx >> 4, d4 = idx & 15;
        relS[0][d4][r] = v.x; relS[1][d4][r] = v.y;
        relS[2][d4][r] = v.z; relS[3][d4][r] = v.w;
    }
    const float4* ent4 = (const float4*)ent;
    #pragma unroll
    for (int k = 0; k < 4; k++) {
        int idx = tx + k * 256;
        int row = idx >> 4, col = idx & 15;
        int v = base + row;
        entL[row * 17 + col] = (v < nE) ? ent4[(size_t)v * 16 + col]
                                        : make_float4(0.f, 0.f, 0.f, 0.f);
    }
    __syncthreads();

    float acc[4][2] = {{0.f,0.f},{0.f,0.f},{0.f,0.f},{0.f,0.f}};
    int r0 = rg * 2;
    #pragma unroll 2
    for (int d4 = 0; d4 < 16; d4++) {
        float4 a0 = entL[(vg * 4 + 0) * 17 + d4];
        float4 a1 = entL[(vg * 4 + 1) * 17 + d4];
        float4 a2 = entL[(vg * 4 + 2) * 17 + d4];
        float4 a3 = entL[(vg * 4 + 3) * 17 + d4];
        float bx0 = relS[0][d4][r0],     by0 = relS[1][d4][r0];
        float bz0 = relS[2][d4][r0],     bw0 = relS[3][d4][r0];
        float bx1 = relS[0][d4][r0 + 1], by1 = relS[1][d4][r0 + 1];
        float bz1 = relS[2][d4][r0 + 1], bw1 = relS[3][d4][r0 + 1];
        acc[0][0] = fmaf(a0.x,bx0, fmaf(a0.y,by0, fmaf(a0.z,bz0, fmaf(a0.w,bw0, acc[0][0]))));
        acc[1][0] = fmaf(a1.x,bx0, fmaf(a1.y,by0, fmaf(a1.z,bz0, fmaf(a1.w,bw0, acc[1][0]))));
        acc[2][0] = fmaf(a2.x,bx0, fmaf(a2.y,by0, fmaf(a2.z,bz0, fmaf(a2.w,bw0, acc[2][0]))));
        acc[3][0] = fmaf(a3.x,bx0, fmaf(a3.y,by0, fmaf(a3.z,bz0, fmaf(a3.w,bw0, acc[3][0]))));
        acc[0][1] = fmaf(a0.x,bx1, fmaf(a0.y,by1, fmaf(a0.z,bz1, fmaf(a0.w,bw1, acc[0][1]))));
        acc[1][1] = fmaf(a1.x,bx1, fmaf(a1.y,by1, fmaf(a1.z,bz1, fmaf(a1.w,bw1, acc[1][1]))));
        acc[2][1] = fmaf(a2.x,bx1, fmaf(a2.y,by1, fmaf(a2.z,bz1, fmaf(a2.w,bw1, acc[2][1]))));
        acc[3][1] = fmaf(a3.x,bx1, fmaf(a3.y,by1, fmaf(a3.z,bz1, fmaf(a3.w,bw1, acc[3][1]))));
    }
    __hip_bfloat162* M2 = (__hip_bfloat162*)M;
    #pragma unroll
    for (int i = 0; i < 4; i++) {
        int v = base + vg * 4 + i;
        if (v < nE) {
            __hip_bfloat16 h0 = __float2bfloat16(acc[i][0] * 0.125f);
            __hip_bfloat16 h1 = __float2bfloat16(acc[i][1] * 0.125f);
            M2[(size_t)v * 16 + rg] = __halves2bfloat162(h0, h1);
        }
    }
}

// ---- Scan step 1: per-block reduce of packed byte counters ----
__global__ __launch_bounds__(SCAN_B) void scan_partial(
    const unsigned int* __restrict__ degP, unsigned int* __restrict__ part, int nW) {
    __shared__ unsigned int lds[SCAN_B];
    int i = blockIdx.x * SCAN_B + threadIdx.x;
    unsigned int v = (i < nW) ? degP[i] : 0u;
    lds[threadIdx.x] = (v & 0xFFu) + ((v >> 8) & 0xFFu) + ((v >> 16) & 0xFFu) + (v >> 24);
    __syncthreads();
    for (int off = SCAN_B >> 1; off > 0; off >>= 1) {
        if (threadIdx.x < off) lds[threadIdx.x] += lds[threadIdx.x + off];
        __syncthreads();
    }
    if (threadIdx.x == 0) part[blockIdx.x] = lds[0];
}

// ---- Scan step 2: single-block exclusive scan of partials ----
__global__ __launch_bounds__(1024) void scan_block(unsigned int* __restrict__ part, int nb) {
    __shared__ unsigned int lds[1024];
    int t = threadIdx.x;
    unsigned int v = (t < nb) ? part[t] : 0u;
    lds[t] = v;
    __syncthreads();
    for (int off = 1; off < 1024; off <<= 1) {
        unsigned int x = (t >= off) ? lds[t - off] : 0u;
        __syncthreads();
        lds[t] += x;
        __syncthreads();
    }
    if (t < nb) part[t] = lds[t] - v;
}

// ---- Scan step 3: per-word byte-expand + block scan -> offs (uint4 stores) ----
__global__ __launch_bounds__(SCAN_B) void scan_final(
    const unsigned int* __restrict__ degP, const unsigned int* __restrict__ part,
    unsigned int* __restrict__ offs, int nW) {
    __shared__ unsigned int lds[SCAN_B];
    int t = threadIdx.x;
    int i = blockIdx.x * SCAN_B + t;
    unsigned int v = (i < nW) ? degP[i] : 0u;
    unsigned int b0 = v & 0xFFu, b1 = (v >> 8) & 0xFFu, b2 = (v >> 16) & 0xFFu, b3 = v >> 24;
    unsigned int tot = b0 + b1 + b2 + b3;
    lds[t] = tot;
    __syncthreads();
    for (int off = 1; off < SCAN_B; off <<= 1) {
        unsigned int x = (t >= off) ? lds[t - off] : 0u;
        __syncthreads();
        lds[t] += x;
        __syncthreads();
    }
    if (i < nW) {
        unsigned int base = part[blockIdx.x] + lds[t] - tot;
        uint4 o;
        o.x = base; o.y = base + b0; o.z = base + b0 + b1; o.w = base + b0 + b1 + b2;
        ((uint4*)offs)[i] = o;
    }
}

// ---- Scatter (atomic-free, index-only payloads) ----
__global__ __launch_bounds__(256) void scatter32(
    const int* __restrict__ head, const int* __restrict__ tail, const int* __restrict__ etype,
    const int* __restrict__ uidx, const int* __restrict__ iidx, const int* __restrict__ ttype,
    const unsigned char* __restrict__ rank_e, const unsigned char* __restrict__ rank_i,
    const unsigned int* __restrict__ offs,
    unsigned int* __restrict__ pay, unsigned int* __restrict__ payu,
    int E, int I, int nE) {
    int t = blockIdx.x * blockDim.x + threadIdx.x;
    if (t < E) {
        unsigned int p = offs[head[t]] + rank_e[t];
        unsigned int v = (unsigned int)tail[t] | ((unsigned int)(etype[t] - 1) << 18);
        __builtin_nontemporal_store(v, &pay[p]);
    } else if (t < E + I) {
        int e = t - E;
        unsigned int p = offs[nE + uidx[e]] + rank_i[e] - (unsigned)E;
        unsigned int v = (unsigned int)iidx[e] | ((unsigned int)ttype[e] << 27);
        __builtin_nontemporal_store(v, &payu[p]);
    }
}

// ============ Kernel C: entity-agg blocks + user-fused blocks ============
__global__ __launch_bounds__(256) void fused_agg(
    const float* __restrict__ ent, const float* __restrict__ usr,
    const float* __restrict__ itc, const __hip_bfloat16* __restrict__ M,
    const unsigned int* __restrict__ pay, const unsigned int* __restrict__ payu,
    const unsigned int* __restrict__ degP, const unsigned int* __restrict__ offs,
    float* __restrict__ patt, float2* __restrict__ msum,
    float* __restrict__ aggE, float* __restrict__ aggU,
    int nE, int nU, int E, int gAE) {
    __shared__ float4 itcL[8][16];
    int tx = threadIdx.x;
    int bid = blockIdx.x;

    if (bid < gAE) {
        // ---- entity segments: online softmax, score via M lookup, 2-deep prefetch ----
        int t = bid * 256 + tx;
        int h = t >> 4, l = t & 15;
        if (h >= nE) return;
        unsigned int d = (degP[h >> 2] >> (8 * (h & 3))) & 0xFFu;
        float m = -3.0e38f, s = 0.f, inv = 0.f;
        float4 acc = make_float4(0.f, 0.f, 0.f, 0.f);
        if (d) {
            unsigned int off = offs[h];
            unsigned int v0 = pay[off];
            float sc0 = __bfloat162float(M[(size_t)(v0 & 0x3FFFFu) * RELS + (v0 >> 18)]);
            float4 a0 = ((const float4*)(ent + (size_t)(v0 & 0x3FFFFu) * DIM))[l];
            for (unsigned int j = 0; j < d; j++) {
                float sc1 = sc0; float4 a1 = a0;
                if (j + 1 < d) {
                    unsigned int v1 = pay[off + j + 1];
                    sc1 = __bfloat162float(M[(size_t)(v1 & 0x3FFFFu) * RELS + (v1 >> 18)]);
                    a1 = ((const float4*)(ent + (size_t)(v1 & 0x3FFFFu) * DIM))[l];
                }
                float mn = fmaxf(m, sc0);
                float scale = __expf(m - mn);
                float w = __expf(sc0 - mn);
                s = s * scale + w;
                acc.x = acc.x * scale + w * a0.x;
                acc.y = acc.y * scale + w * a0.y;
                acc.z = acc.z * scale + w * a0.z;
                acc.w = acc.w * scale + w * a0.w;
                m = mn; sc0 = sc1; a0 = a1;
            }
            inv = 1.f / s;
        }
        if (l == 0) msum[h] = make_float2(m, inv);
        acc.x *= inv; acc.y *= inv; acc.z *= inv; acc.w *= inv;
        ((float4*)(aggE + (size_t)h * DIM))[l] = acc;
        return;
    }

    // ---- user segments: fused score + online softmax + aggregate ----
    if (tx < 128) itcL[tx >> 4][tx & 15] = ((const float4*)itc)[tx];
    __syncthreads();
    int t = (bid - gAE) * 256 + tx;
    int h = t >> 4, l = t & 15;
    if (h >= nU) return;
    int hs = nE + h;
    unsigned int d = (degP[hs >> 2] >> (8 * (hs & 3))) & 0xFFu;
    float m = -3.0e38f, s = 0.f, inv = 0.f;
    float4 acc = make_float4(0.f, 0.f, 0.f, 0.f);
    float4 ur = ((const float4*)(usr + (size_t)h * DIM))[l];
    if (d) {
        unsigned int off = offs[hs] - (unsigned)E;
        unsigned int v0 = payu[off];
        float4 a0 = ((const float4*)(ent + (size_t)(v0 & 0x7ffffffu) * DIM))[l];
        for (unsigned int j = 0; j < d; j++) {
            unsigned int v1 = v0; float4 a1 = a0;
            if (j + 1 < d) {
                v1 = payu[off + j + 1];
                a1 = ((const float4*)(ent + (size_t)(v1 & 0x7ffffffu) * DIM))[l];
            }
            float4 c = itcL[v0 >> 27][l];
            float p = a0.x * ur.x * c.x + a0.y * ur.y * c.y
                    + a0.z * ur.z * c.z + a0.w * ur.w * c.w;
            p += __shfl_xor(p, 1);
            p += __shfl_xor(p, 2);
            p += __shfl_xor(p, 4);
            p += __shfl_xor(p, 8);
            if (l == 0) patt[off + j] = p;
            float mn = fmaxf(m, p);
            float scale = __expf(m - mn);
            float w = __expf(p - mn);
            s = s * scale + w;
            acc.x = acc.x * scale + w * a0.x;
            acc.y = acc.y * scale + w * a0.y;
            acc.z = acc.z * scale + w * a0.z;
            acc.w = acc.w * scale + w * a0.w;
            m = mn; v0 = v1; a0 = a1;
        }
        inv = 1.f / s;
    }
    if (l == 0) msum[hs] = make_float2(m, inv);
    acc.x *= inv; acc.y *= inv; acc.z *= inv; acc.w *= inv;
    ((float4*)(aggU + (size_t)h * DIM))[l] = acc;
}

// ---- Epilogue: coalesced per-edge weight writes ----
__global__ __launch_bounds__(256) void wout(
    const int* __restrict__ head, const int* __restrict__ tail, const int* __restrict__ etype,
    const int* __restrict__ uidx,
    const __hip_bfloat16* __restrict__ M, const float* __restrict__ patt,
    const unsigned char* __restrict__ rank_i,
    const unsigned int* __restrict__ offs, const float2* __restrict__ msum,
    float* __restrict__ w1, float* __restrict__ attw, int E, int I, int nE) {
    int t = blockIdx.x * blockDim.x + threadIdx.x;
    if (t < E) {
        float2 mi = msum[head[t]];
        float sc = __bfloat162float(M[(size_t)tail[t] * RELS + (etype[t] - 1)]);
        w1[t] = __expf(sc - mi.x) * mi.y;
    } else if (t < E + I) {
        int e = t - E; int u = uidx[e];
        float2 mi = msum[nE + u];
        float sc = patt[offs[nE + u] - (unsigned)E + rank_i[e]];
        attw[e] = __expf(sc - mi.x) * mi.y;
    }
}

extern "C" void kernel_launch(void* const* d_in, const int* in_sizes, int n_in,
                              void* d_out, int out_size, void* d_ws, size_t ws_size,
                              hipStream_t stream) {
    const float* ent  = (const float*)d_in[0];
    const float* usr  = (const float*)d_in[1];
    const float* itc  = (const float*)d_in[2];
    const float* rel  = (const float*)d_in[3];
    const int* eidx   = (const int*)d_in[4];
    const int* etype  = (const int*)d_in[5];
    const int* uidx   = (const int*)d_in[6];
    const int* iidx   = (const int*)d_in[7];
    const int* ttype  = (const int*)d_in[8];

    const int E  = in_sizes[4] / 2;
    const int I  = in_sizes[6];
    const int nE = in_sizes[0] / DIM;
    const int nU = in_sizes[1] / DIM;
    const int* head = eidx;
    const int* tail = eidx + E;
    const int NSEG = nE + nU;
    const int NW = (NSEG + 3) / 4;                 // packed words
    const int NWpad = (NW + 3) & ~3;               // 16B-aligned word count
    const int NB = (NW + SCAN_B - 1) / SCAN_B;     // scan blocks <= 1024

    float* out_entity = (float*)d_out;
    float* out_user   = out_entity + (size_t)nE * DIM;
    float* out_attw   = out_user + (size_t)nU * DIM;
    float* out_w1     = out_attw + I;

    // workspace layout (u32 units; 16B alignment preserved)
    unsigned int* degP    = (unsigned int*)d_ws;            // NWpad
    unsigned int* offs    = degP + NWpad;                   // NSEG
    unsigned int* part    = offs + NSEG;                    // 1024
    unsigned char* rank_e = (unsigned char*)(part + 1024);  // E bytes
    unsigned char* rank_i = rank_e + E;                     // I bytes
    unsigned int* pay     = (unsigned int*)(rank_i + I);    // E
    unsigned int* payu    = pay + E;                        // I
    __hip_bfloat16* M     = (__hip_bfloat16*)(payu + I);    // nE*RELS bf16
    float2* msum          = (float2*)(M + (size_t)nE * RELS); // NSEG
    float* patt           = (float*)(msum + NSEG);          // I

    hipMemsetAsync(degP, 0, (size_t)NWpad * sizeof(unsigned int), stream);

    const int T = 256;
    const int gM  = (nE + TILE_V - 1) / TILE_V;
    const int gD  = (E + I + T - 1) / T;
    const int gAE = (int)(((size_t)nE * 16 + T - 1) / T);
    const int gAU = (int)(((size_t)nU * 16 + T - 1) / T);

    // A: build_M blocks + degree blocks (independent, co-scheduled)
    buildM_deg<<<dim3((unsigned)(gM + gD)), T, 0, stream>>>(
        ent, rel, M, head, uidx, degP, rank_e, rank_i, nE, E, I, gM);

    // scans over packed degree bytes -> CSR offsets
    scan_partial<<<dim3((unsigned)NB), SCAN_B, 0, stream>>>(degP, part, NW);
    scan_block<<<dim3(1), 1024, 0, stream>>>(part, NB);
    scan_final<<<dim3((unsigned)NB), SCAN_B, 0, stream>>>(degP, part, offs, NW);

    // atomic-free scatter of index payloads
    scatter32<<<dim3((unsigned)gD), T, 0, stream>>>(
        head, tail, etype, uidx, iidx, ttype, rank_e, rank_i, offs, pay, payu, E, I, nE);

    // C: entity-agg blocks + user-fused blocks (co-scheduled)
    fused_agg<<<dim3((unsigned)(gAE + gAU)), T, 0, stream>>>(
        ent, usr, itc, M, pay, payu, degP, offs, patt, msum,
        out_entity, out_user, nE, nU, E, gAE);

    // coalesced per-edge weights
    wout<<<dim3((unsigned)gD), T, 0, stream>>>(
        head, tail, etype, uidx, M, patt, rank_i, offs, msum, out_w1, out_attw, E, I, nE);
}

// Round 10
// 312.866 us; speedup vs baseline: 1.3489x; 1.0640x over previous
//
#include <hip/hip_runtime.h>
#include <hip/hip_bf16.h>

#define DIM 64
#define RELS 32
#define SCAN_B 512
#define TILE_V 64

// ---- manual bf16 helpers (RNE pack, shift decode) ----
__device__ __forceinline__ unsigned int pk_bf2(float a, float b) {
    unsigned int ua = __float_as_uint(a);
    unsigned int ub = __float_as_uint(b);
    ua = (ua + 0x7fffu + ((ua >> 16) & 1u)) >> 16;
    ub = (ub + 0x7fffu + ((ub >> 16) & 1u)) >> 16;
    return ua | (ub << 16);
}
__device__ __forceinline__ float4 bf4_to_f4(uint2 u) {
    float4 r;
    r.x = __uint_as_float(u.x << 16);
    r.y = __uint_as_float(u.x & 0xffff0000u);
    r.z = __uint_as_float(u.y << 16);
    r.w = __uint_as_float(u.y & 0xffff0000u);
    return r;
}

// ============ Kernel A: build_M + entB blocks + packed-degree-count blocks ============
__global__ __launch_bounds__(256, 4) void buildM_deg(
    const float* __restrict__ ent, const float* __restrict__ rel,
    __hip_bfloat16* __restrict__ M, uint2* __restrict__ entB2,
    const int* __restrict__ head, const int* __restrict__ uidx,
    unsigned int* __restrict__ degP,
    unsigned char* __restrict__ rank_e, unsigned char* __restrict__ rank_i,
    int nE, int E, int I, int gM) {
    __shared__ float4 entL[TILE_V * 17];
    __shared__ float relS[4][16][33];
    int tx = threadIdx.x;
    int bid = blockIdx.x;

    if (bid >= gM) {
        // ---- degree/rank blocks (packed byte counters) ----
        int t = (bid - gM) * 256 + tx;
        if (t < E) {
            int s = head[t];
            unsigned int old = atomicAdd(&degP[s >> 2], 1u << (8 * (s & 3)));
            rank_e[t] = (unsigned char)((old >> (8 * (s & 3))) & 0xFFu);
        } else if (t < E + I) {
            int e = t - E;
            int s = nE + uidx[e];
            unsigned int old = atomicAdd(&degP[s >> 2], 1u << (8 * (s & 3)));
            rank_i[e] = (unsigned char)((old >> (8 * (s & 3))) & 0xFFu);
        }
        return;
    }

    // ---- build_M blocks (also emit bf16 entity mirror for the entity-agg path) ----
    int vg = tx >> 4, rg = tx & 15;
    int base = bid * TILE_V;
    const float4* rel4 = (const float4*)rel;
    #pragma unroll
    for (int k = 0; k < 2; k++) {
        int idx = tx + k * 256;
        float4 v = rel4[idx];
        int r = idx >> 4, d4 = idx & 15;
        relS[0][d4][r] = v.x; relS[1][d4][r] = v.y;
        relS[2][d4][r] = v.z; relS[3][d4][r] = v.w;
    }
    const float4* ent4 = (const float4*)ent;
    #pragma unroll
    for (int k = 0; k < 4; k++) {
        int idx = tx + k * 256;
        int row = idx >> 4, col = idx & 15;
        int v = base + row;
        float4 val = make_float4(0.f, 0.f, 0.f, 0.f);
        if (v < nE) {
            val = ent4[(size_t)v * 16 + col];
            entB2[(size_t)v * 16 + col] = make_uint2(pk_bf2(val.x, val.y), pk_bf2(val.z, val.w));
        }
        entL[row * 17 + col] = val;
    }
    __syncthreads();

    float acc[4][2] = {{0.f,0.f},{0.f,0.f},{0.f,0.f},{0.f,0.f}};
    int r0 = rg * 2;
    #pragma unroll 2
    for (int d4 = 0; d4 < 16; d4++) {
        float4 a0 = entL[(vg * 4 + 0) * 17 + d4];
        float4 a1 = entL[(vg * 4 + 1) * 17 + d4];
        float4 a2 = entL[(vg * 4 + 2) * 17 + d4];
        float4 a3 = entL[(vg * 4 + 3) * 17 + d4];
        float bx0 = relS[0][d4][r0],     by0 = relS[1][d4][r0];
        float bz0 = relS[2][d4][r0],     bw0 = relS[3][d4][r0];
        float bx1 = relS[0][d4][r0 + 1], by1 = relS[1][d4][r0 + 1];
        float bz1 = relS[2][d4][r0 + 1], bw1 = relS[3][d4][r0 + 1];
        acc[0][0] = fmaf(a0.x,bx0, fmaf(a0.y,by0, fmaf(a0.z,bz0, fmaf(a0.w,bw0, acc[0][0]))));
        acc[1][0] = fmaf(a1.x,bx0, fmaf(a1.y,by0, fmaf(a1.z,bz0, fmaf(a1.w,bw0, acc[1][0]))));
        acc[2][0] = fmaf(a2.x,bx0, fmaf(a2.y,by0, fmaf(a2.z,bz0, fmaf(a2.w,bw0, acc[2][0]))));
        acc[3][0] = fmaf(a3.x,bx0, fmaf(a3.y,by0, fmaf(a3.z,bz0, fmaf(a3.w,bw0, acc[3][0]))));
        acc[0][1] = fmaf(a0.x,bx1, fmaf(a0.y,by1, fmaf(a0.z,bz1, fmaf(a0.w,bw1, acc[0][1]))));
        acc[1][1] = fmaf(a1.x,bx1, fmaf(a1.y,by1, fmaf(a1.z,bz1, fmaf(a1.w,bw1, acc[1][1]))));
        acc[2][1] = fmaf(a2.x,bx1, fmaf(a2.y,by1, fmaf(a2.z,bz1, fmaf(a2.w,bw1, acc[2][1]))));
        acc[3][1] = fmaf(a3.x,bx1, fmaf(a3.y,by1, fmaf(a3.z,bz1, fmaf(a3.w,bw1, acc[3][1]))));
    }
    __hip_bfloat162* M2 = (__hip_bfloat162*)M;
    #pragma unroll
    for (int i = 0; i < 4; i++) {
        int v = base + vg * 4 + i;
        if (v < nE) {
            __hip_bfloat16 h0 = __float2bfloat16(acc[i][0] * 0.125f);
            __hip_bfloat16 h1 = __float2bfloat16(acc[i][1] * 0.125f);
            M2[(size_t)v * 16 + rg] = __halves2bfloat162(h0, h1);
        }
    }
}

// ---- Scan step 1: per-block reduce of packed byte counters ----
__global__ __launch_bounds__(SCAN_B) void scan_partial(
    const unsigned int* __restrict__ degP, unsigned int* __restrict__ part, int nW) {
    __shared__ unsigned int lds[SCAN_B];
    int i = blockIdx.x * SCAN_B + threadIdx.x;
    unsigned int v = (i < nW) ? degP[i] : 0u;
    lds[threadIdx.x] = (v & 0xFFu) + ((v >> 8) & 0xFFu) + ((v >> 16) & 0xFFu) + (v >> 24);
    __syncthreads();
    for (int off = SCAN_B >> 1; off > 0; off >>= 1) {
        if (threadIdx.x < off) lds[threadIdx.x] += lds[threadIdx.x + off];
        __syncthreads();
    }
    if (threadIdx.x == 0) part[blockIdx.x] = lds[0];
}

// ---- Scan step 2: single-block exclusive scan of partials ----
__global__ __launch_bounds__(1024) void scan_block(unsigned int* __restrict__ part, int nb) {
    __shared__ unsigned int lds[1024];
    int t = threadIdx.x;
    unsigned int v = (t < nb) ? part[t] : 0u;
    lds[t] = v;
    __syncthreads();
    for (int off = 1; off < 1024; off <<= 1) {
        unsigned int x = (t >= off) ? lds[t - off] : 0u;
        __syncthreads();
        lds[t] += x;
        __syncthreads();
    }
    if (t < nb) part[t] = lds[t] - v;
}

// ---- Scan step 3: per-word byte-expand + block scan -> offs ----
__global__ __launch_bounds__(SCAN_B) void scan_final(
    const unsigned int* __restrict__ degP, const unsigned int* __restrict__ part,
    unsigned int* __restrict__ offs, int nW) {
    __shared__ unsigned int lds[SCAN_B];
    int t = threadIdx.x;
    int i = blockIdx.x * SCAN_B + t;
    unsigned int v = (i < nW) ? degP[i] : 0u;
    unsigned int b0 = v & 0xFFu, b1 = (v >> 8) & 0xFFu, b2 = (v >> 16) & 0xFFu, b3 = v >> 24;
    unsigned int tot = b0 + b1 + b2 + b3;
    lds[t] = tot;
    __syncthreads();
    for (int off = 1; off < SCAN_B; off <<= 1) {
        unsigned int x = (t >= off) ? lds[t - off] : 0u;
        __syncthreads();
        lds[t] += x;
        __syncthreads();
    }
    if (i < nW) {
        unsigned int base = part[blockIdx.x] + lds[t] - tot;
        uint4 o;
        o.x = base; o.y = base + b0; o.z = base + b0 + b1; o.w = base + b0 + b1 + b2;
        ((uint4*)offs)[i] = o;
    }
}

// ---- Scatter: single random-M pass; pay64={score,tail}; e_sc in edge order ----
__global__ __launch_bounds__(256) void scatter32(
    const __hip_bfloat16* __restrict__ M,
    const int* __restrict__ head, const int* __restrict__ tail, const int* __restrict__ etype,
    const int* __restrict__ uidx, const int* __restrict__ iidx, const int* __restrict__ ttype,
    const unsigned char* __restrict__ rank_e, const unsigned char* __restrict__ rank_i,
    const unsigned int* __restrict__ offs,
    unsigned long long* __restrict__ pay64, unsigned int* __restrict__ payu,
    float* __restrict__ e_sc, int E, int I, int nE) {
    int t = blockIdx.x * blockDim.x + threadIdx.x;
    if (t < E) {
        int tl = tail[t];
        float sc = __bfloat162float(M[(size_t)tl * RELS + (etype[t] - 1)]);
        e_sc[t] = sc;
        unsigned int p = offs[head[t]] + rank_e[t];
        unsigned long long v = ((unsigned long long)__float_as_uint(sc) << 32) | (unsigned int)tl;
        __builtin_nontemporal_store(v, &pay64[p]);
    } else if (t < E + I) {
        int e = t - E;
        unsigned int p = offs[nE + uidx[e]] + rank_i[e] - (unsigned)E;
        unsigned int v = (unsigned int)iidx[e] | ((unsigned int)ttype[e] << 27);
        __builtin_nontemporal_store(v, &payu[p]);
    }
}

// ============ Kernel C: entity-agg (bf16 rows) + user-fused (f32 rows) ============
__global__ __launch_bounds__(256) void fused_agg(
    const uint2* __restrict__ entB2, const float* __restrict__ ent,
    const float* __restrict__ usr, const float* __restrict__ itc,
    const unsigned long long* __restrict__ pay64, const unsigned int* __restrict__ payu,
    const unsigned int* __restrict__ degP, const unsigned int* __restrict__ offs,
    float* __restrict__ patt, float2* __restrict__ msum,
    float* __restrict__ aggE, float* __restrict__ aggU,
    int nE, int nU, int E, int gAE) {
    __shared__ float4 itcL[8][16];
    int tx = threadIdx.x;
    int bid = blockIdx.x;

    if (bid < gAE) {
        // ---- entity segments: sequential pay64 scores, bf16 row gather (2 lines/row) ----
        int t = bid * 256 + tx;
        int h = t >> 4, l = t & 15;
        if (h >= nE) return;
        unsigned int d = (degP[h >> 2] >> (8 * (h & 3))) & 0xFFu;
        float m = -3.0e38f, s = 0.f, inv = 0.f;
        float4 acc = make_float4(0.f, 0.f, 0.f, 0.f);
        if (d) {
            unsigned int off = offs[h];
            unsigned long long v0 = pay64[off];
            uint2 b0 = entB2[(size_t)(unsigned int)(v0 & 0xffffffffu) * 16 + l];
            for (unsigned int j = 0; j < d; j++) {
                unsigned long long v1 = v0; uint2 b1 = b0;
                if (j + 1 < d) {
                    v1 = pay64[off + j + 1];
                    b1 = entB2[(size_t)(unsigned int)(v1 & 0xffffffffu) * 16 + l];
                }
                float sc = __uint_as_float((unsigned int)(v0 >> 32));
                float4 a0 = bf4_to_f4(b0);
                float mn = fmaxf(m, sc);
                float scale = __expf(m - mn);
                float w = __expf(sc - mn);
                s = s * scale + w;
                acc.x = acc.x * scale + w * a0.x;
                acc.y = acc.y * scale + w * a0.y;
                acc.z = acc.z * scale + w * a0.z;
                acc.w = acc.w * scale + w * a0.w;
                m = mn; v0 = v1; b0 = b1;
            }
            inv = 1.f / s;
        }
        if (l == 0) msum[h] = make_float2(m, inv);
        acc.x *= inv; acc.y *= inv; acc.z *= inv; acc.w *= inv;
        ((float4*)(aggE + (size_t)h * DIM))[l] = acc;
        return;
    }

    // ---- user segments: f32 rows (score precision), fused softmax + aggregate ----
    if (tx < 128) itcL[tx >> 4][tx & 15] = ((const float4*)itc)[tx];
    __syncthreads();
    int t = (bid - gAE) * 256 + tx;
    int h = t >> 4, l = t & 15;
    if (h >= nU) return;
    int hs = nE + h;
    unsigned int d = (degP[hs >> 2] >> (8 * (hs & 3))) & 0xFFu;
    float m = -3.0e38f, s = 0.f, inv = 0.f;
    float4 acc = make_float4(0.f, 0.f, 0.f, 0.f);
    float4 ur = ((const float4*)(usr + (size_t)h * DIM))[l];
    if (d) {
        unsigned int off = offs[hs] - (unsigned)E;
        unsigned int v0 = payu[off];
        float4 a0 = ((const float4*)(ent + (size_t)(v0 & 0x7ffffffu) * DIM))[l];
        for (unsigned int j = 0; j < d; j++) {
            unsigned int v1 = v0; float4 a1 = a0;
            if (j + 1 < d) {
                v1 = payu[off + j + 1];
                a1 = ((const float4*)(ent + (size_t)(v1 & 0x7ffffffu) * DIM))[l];
            }
            float4 c = itcL[v0 >> 27][l];
            float p = a0.x * ur.x * c.x + a0.y * ur.y * c.y
                    + a0.z * ur.z * c.z + a0.w * ur.w * c.w;
            p += __shfl_xor(p, 1);
            p += __shfl_xor(p, 2);
            p += __shfl_xor(p, 4);
            p += __shfl_xor(p, 8);
            if (l == 0) patt[off + j] = p;
            float mn = fmaxf(m, p);
            float scale = __expf(m - mn);
            float w = __expf(p - mn);
            s = s * scale + w;
            acc.x = acc.x * scale + w * a0.x;
            acc.y = acc.y * scale + w * a0.y;
            acc.z = acc.z * scale + w * a0.z;
            acc.w = acc.w * scale + w * a0.w;
            m = mn; v0 = v1; a0 = a1;
        }
        inv = 1.f / s;
    }
    if (l == 0) msum[hs] = make_float2(m, inv);
    acc.x *= inv; acc.y *= inv; acc.z *= inv; acc.w *= inv;
    ((float4*)(aggU + (size_t)h * DIM))[l] = acc;
}

// ---- Epilogue: coalesced per-edge weight writes (sequential score reads) ----
__global__ __launch_bounds__(256) void wout(
    const int* __restrict__ head, const int* __restrict__ uidx,
    const float* __restrict__ e_sc, const float* __restrict__ patt,
    const unsigned char* __restrict__ rank_i,
    const unsigned int* __restrict__ offs, const float2* __restrict__ msum,
    float* __restrict__ w1, float* __restrict__ attw, int E, int I, int nE) {
    int t = blockIdx.x * blockDim.x + threadIdx.x;
    if (t < E) {
        float2 mi = msum[head[t]];
        w1[t] = __expf(e_sc[t] - mi.x) * mi.y;
    } else if (t < E + I) {
        int e = t - E; int u = uidx[e];
        float2 mi = msum[nE + u];
        float sc = patt[offs[nE + u] - (unsigned)E + rank_i[e]];
        attw[e] = __expf(sc - mi.x) * mi.y;
    }
}

extern "C" void kernel_launch(void* const* d_in, const int* in_sizes, int n_in,
                              void* d_out, int out_size, void* d_ws, size_t ws_size,
                              hipStream_t stream) {
    const float* ent  = (const float*)d_in[0];
    const float* usr  = (const float*)d_in[1];
    const float* itc  = (const float*)d_in[2];
    const float* rel  = (const float*)d_in[3];
    const int* eidx   = (const int*)d_in[4];
    const int* etype  = (const int*)d_in[5];
    const int* uidx   = (const int*)d_in[6];
    const int* iidx   = (const int*)d_in[7];
    const int* ttype  = (const int*)d_in[8];

    const int E  = in_sizes[4] / 2;
    const int I  = in_sizes[6];
    const int nE = in_sizes[0] / DIM;
    const int nU = in_sizes[1] / DIM;
    const int* head = eidx;
    const int* tail = eidx + E;
    const int NSEG = nE + nU;
    const int NW = (NSEG + 3) / 4;
    const int NWpad = (NW + 3) & ~3;
    const int NB = (NW + SCAN_B - 1) / SCAN_B;

    float* out_entity = (float*)d_out;
    float* out_user   = out_entity + (size_t)nE * DIM;
    float* out_attw   = out_user + (size_t)nU * DIM;
    float* out_w1     = out_attw + I;

    // workspace layout (u32 units; 8/16B alignment preserved by even offsets)
    unsigned int* degP      = (unsigned int*)d_ws;                 // NWpad
    unsigned int* offs      = degP + NWpad;                        // NSEG
    unsigned int* part      = offs + NSEG;                         // 1024
    unsigned long long* pay64 = (unsigned long long*)(part + 1024); // E u64
    unsigned int* payu      = (unsigned int*)(pay64 + E);          // I
    float* e_sc             = (float*)(payu + I);                  // E
    __hip_bfloat16* M       = (__hip_bfloat16*)(e_sc + E);         // nE*RELS bf16
    uint2* entB2            = (uint2*)(M + (size_t)nE * RELS);     // nE*16 uint2
    float2* msum            = (float2*)(entB2 + (size_t)nE * 16);  // NSEG
    float* patt             = (float*)(msum + NSEG);               // I
    unsigned char* rank_e   = (unsigned char*)(patt + I);          // E bytes
    unsigned char* rank_i   = rank_e + E;                          // I bytes

    hipMemsetAsync(degP, 0, (size_t)NWpad * sizeof(unsigned int), stream);

    const int T = 256;
    const int gM  = (nE + TILE_V - 1) / TILE_V;
    const int gD  = (E + I + T - 1) / T;
    const int gAE = (int)(((size_t)nE * 16 + T - 1) / T);
    const int gAU = (int)(((size_t)nU * 16 + T - 1) / T);

    buildM_deg<<<dim3((unsigned)(gM + gD)), T, 0, stream>>>(
        ent, rel, M, entB2, head, uidx, degP, rank_e, rank_i, nE, E, I, gM);

    scan_partial<<<dim3((unsigned)NB), SCAN_B, 0, stream>>>(degP, part, NW);
    scan_block<<<dim3(1), 1024, 0, stream>>>(part, NB);
    scan_final<<<dim3((unsigned)NB), SCAN_B, 0, stream>>>(degP, part, offs, NW);

    scatter32<<<dim3((unsigned)gD), T, 0, stream>>>(
        M, head, tail, etype, uidx, iidx, ttype, rank_e, rank_i, offs,
        pay64, payu, e_sc, E, I, nE);

    fused_agg<<<dim3((unsigned)(gAE + gAU)), T, 0, stream>>>(
        entB2, ent, usr, itc, pay64, payu, degP, offs, patt, msum,
        out_entity, out_user, nE, nU, E, gAE);

    wout<<<dim3((unsigned)gD), T, 0, stream>>>(
        head, uidx, e_sc, patt, rank_i, offs, msum, out_w1, out_attw, E, I, nE);
}

// Round 11
// 291.212 us; speedup vs baseline: 1.4492x; 1.0744x over previous
//
#include <hip/hip_runtime.h>
#include <hip/hip_bf16.h>
#include <hip/hip_fp16.h>

#define DIM 64
#define RELS 32
#define SCAN_B 512
#define TILE_V 64

// ---- fp16 helpers: pack 2 floats -> u32, decode uint2 (4 halves) -> float4 ----
__device__ __forceinline__ unsigned int pk_h2(float a, float b) {
    __half2 h = __float22half2_rn(make_float2(a, b));
    return *reinterpret_cast<unsigned int*>(&h);
}
__device__ __forceinline__ float4 h4_to_f4(uint2 u) {
    __half2 h0 = *reinterpret_cast<__half2*>(&u.x);
    __half2 h1 = *reinterpret_cast<__half2*>(&u.y);
    float2 f0 = __half22float2(h0);
    float2 f1 = __half22float2(h1);
    return make_float4(f0.x, f0.y, f1.x, f1.y);
}

// ============ Kernel A: build_M + fp16 mirror, INTERLEAVED with degree/rank ============
// bid%7: slots 0-1 = build blocks, slots 2-6 = degree blocks -> both types co-resident,
// so the VALU/LDS build phase hides under the atomic-latency degree phase.
__global__ __launch_bounds__(256, 4) void buildM_deg(
    const float* __restrict__ ent, const float* __restrict__ rel,
    __hip_bfloat16* __restrict__ M, uint2* __restrict__ entH,
    const int* __restrict__ head, const int* __restrict__ uidx,
    unsigned int* __restrict__ deg,
    unsigned char* __restrict__ rank_e, unsigned char* __restrict__ rank_i,
    int nE, int E, int I, int gM) {
    __shared__ float4 entL[TILE_V * 17];
    __shared__ float relS[4][16][33];
    int tx = threadIdx.x;
    int bid = blockIdx.x;
    int g = bid / 7, slot = bid - g * 7;

    if (slot >= 2) {
        // ---- degree/rank blocks: plain u32 counters (packed bytes had 4x word contention) ----
        int t = (g * 5 + (slot - 2)) * 256 + tx;
        if (t < E) {
            rank_e[t] = (unsigned char)atomicAdd(&deg[head[t]], 1u);
        } else if (t < E + I) {
            int e = t - E;
            rank_i[e] = (unsigned char)atomicAdd(&deg[nE + uidx[e]], 1u);
        }
        return;
    }

    // ---- build blocks ----
    int mb = g * 2 + slot;
    if (mb >= gM) return;
    int vg = tx >> 4, rg = tx & 15;
    int base = mb * TILE_V;
    const float4* rel4 = (const float4*)rel;
    #pragma unroll
    for (int k = 0; k < 2; k++) {
        int idx = tx + k * 256;
        float4 v = rel4[idx];
        int r = idx >> 4, d4 = idx & 15;
        relS[0][d4][r] = v.x; relS[1][d4][r] = v.y;
        relS[2][d4][r] = v.z; relS[3][d4][r] = v.w;
    }
    const float4* ent4 = (const float4*)ent;
    #pragma unroll
    for (int k = 0; k < 4; k++) {
        int idx = tx + k * 256;
        int row = idx >> 4, col = idx & 15;
        int v = base + row;
        float4 val = make_float4(0.f, 0.f, 0.f, 0.f);
        if (v < nE) {
            val = ent4[(size_t)v * 16 + col];
            entH[(size_t)v * 16 + col] = make_uint2(pk_h2(val.x, val.y), pk_h2(val.z, val.w));
        }
        entL[row * 17 + col] = val;
    }
    __syncthreads();

    float acc[4][2] = {{0.f,0.f},{0.f,0.f},{0.f,0.f},{0.f,0.f}};
    int r0 = rg * 2;
    #pragma unroll 2
    for (int d4 = 0; d4 < 16; d4++) {
        float4 a0 = entL[(vg * 4 + 0) * 17 + d4];
        float4 a1 = entL[(vg * 4 + 1) * 17 + d4];
        float4 a2 = entL[(vg * 4 + 2) * 17 + d4];
        float4 a3 = entL[(vg * 4 + 3) * 17 + d4];
        float bx0 = relS[0][d4][r0],     by0 = relS[1][d4][r0];
        float bz0 = relS[2][d4][r0],     bw0 = relS[3][d4][r0];
        float bx1 = relS[0][d4][r0 + 1], by1 = relS[1][d4][r0 + 1];
        float bz1 = relS[2][d4][r0 + 1], bw1 = relS[3][d4][r0 + 1];
        acc[0][0] = fmaf(a0.x,bx0, fmaf(a0.y,by0, fmaf(a0.z,bz0, fmaf(a0.w,bw0, acc[0][0]))));
        acc[1][0] = fmaf(a1.x,bx0, fmaf(a1.y,by0, fmaf(a1.z,bz0, fmaf(a1.w,bw0, acc[1][0]))));
        acc[2][0] = fmaf(a2.x,bx0, fmaf(a2.y,by0, fmaf(a2.z,bz0, fmaf(a2.w,bw0, acc[2][0]))));
        acc[3][0] = fmaf(a3.x,bx0, fmaf(a3.y,by0, fmaf(a3.z,bz0, fmaf(a3.w,bw0, acc[3][0]))));
        acc[0][1] = fmaf(a0.x,bx1, fmaf(a0.y,by1, fmaf(a0.z,bz1, fmaf(a0.w,bw1, acc[0][1]))));
        acc[1][1] = fmaf(a1.x,bx1, fmaf(a1.y,by1, fmaf(a1.z,bz1, fmaf(a1.w,bw1, acc[1][1]))));
        acc[2][1] = fmaf(a2.x,bx1, fmaf(a2.y,by1, fmaf(a2.z,bz1, fmaf(a2.w,bw1, acc[2][1]))));
        acc[3][1] = fmaf(a3.x,bx1, fmaf(a3.y,by1, fmaf(a3.z,bz1, fmaf(a3.w,bw1, acc[3][1]))));
    }
    __hip_bfloat162* M2 = (__hip_bfloat162*)M;
    #pragma unroll
    for (int i = 0; i < 4; i++) {
        int v = base + vg * 4 + i;
        if (v < nE) {
            __hip_bfloat16 h0 = __float2bfloat16(acc[i][0] * 0.125f);
            __hip_bfloat16 h1 = __float2bfloat16(acc[i][1] * 0.125f);
            M2[(size_t)v * 16 + rg] = __halves2bfloat162(h0, h1);
        }
    }
}

// ---- Scan step 1: per-block reduce of u32 degrees ----
__global__ __launch_bounds__(SCAN_B) void scan_partial(
    const unsigned int* __restrict__ deg, unsigned int* __restrict__ part, int n) {
    __shared__ unsigned int lds[SCAN_B];
    int i = blockIdx.x * SCAN_B + threadIdx.x;
    lds[threadIdx.x] = (i < n) ? deg[i] : 0u;
    __syncthreads();
    for (int off = SCAN_B >> 1; off > 0; off >>= 1) {
        if (threadIdx.x < off) lds[threadIdx.x] += lds[threadIdx.x + off];
        __syncthreads();
    }
    if (threadIdx.x == 0) part[blockIdx.x] = lds[0];
}

// ---- Scan step 2: single-block exclusive scan of partials ----
__global__ __launch_bounds__(1024) void scan_block(unsigned int* __restrict__ part, int nb) {
    __shared__ unsigned int lds[1024];
    int t = threadIdx.x;
    unsigned int v = (t < nb) ? part[t] : 0u;
    lds[t] = v;
    __syncthreads();
    for (int off = 1; off < 1024; off <<= 1) {
        unsigned int x = (t >= off) ? lds[t - off] : 0u;
        __syncthreads();
        lds[t] += x;
        __syncthreads();
    }
    if (t < nb) part[t] = lds[t] - v;
}

// ---- Scan step 3: in-block exclusive scan + block offset -> offs ----
__global__ __launch_bounds__(SCAN_B) void scan_final(
    const unsigned int* __restrict__ deg, const unsigned int* __restrict__ part,
    unsigned int* __restrict__ offs, int n) {
    __shared__ unsigned int lds[SCAN_B];
    int t = threadIdx.x;
    int i = blockIdx.x * SCAN_B + t;
    unsigned int v = (i < n) ? deg[i] : 0u;
    lds[t] = v;
    __syncthreads();
    for (int off = 1; off < SCAN_B; off <<= 1) {
        unsigned int x = (t >= off) ? lds[t - off] : 0u;
        __syncthreads();
        lds[t] += x;
        __syncthreads();
    }
    if (i < n) offs[i] = part[blockIdx.x] + lds[t] - v;
}

// ---- Scatter: single random-M pass; pay64={score,tail}; e_sc in edge order ----
__global__ __launch_bounds__(256) void scatter32(
    const __hip_bfloat16* __restrict__ M,
    const int* __restrict__ head, const int* __restrict__ tail, const int* __restrict__ etype,
    const int* __restrict__ uidx, const int* __restrict__ iidx, const int* __restrict__ ttype,
    const unsigned char* __restrict__ rank_e, const unsigned char* __restrict__ rank_i,
    const unsigned int* __restrict__ offs,
    unsigned long long* __restrict__ pay64, unsigned int* __restrict__ payu,
    float* __restrict__ e_sc, int E, int I, int nE) {
    int t = blockIdx.x * blockDim.x + threadIdx.x;
    if (t < E) {
        int tl = tail[t];
        float sc = __bfloat162float(M[(size_t)tl * RELS + (etype[t] - 1)]);
        e_sc[t] = sc;
        unsigned int p = offs[head[t]] + rank_e[t];
        unsigned long long v = ((unsigned long long)__float_as_uint(sc) << 32) | (unsigned int)tl;
        __builtin_nontemporal_store(v, &pay64[p]);
    } else if (t < E + I) {
        int e = t - E;
        unsigned int p = offs[nE + uidx[e]] + rank_i[e] - (unsigned)E;
        unsigned int v = (unsigned int)iidx[e] | ((unsigned int)ttype[e] << 27);
        __builtin_nontemporal_store(v, &payu[p]);
    }
}

// ============ Kernel C: entity-agg + user-fused, both on fp16 rows ============
__global__ __launch_bounds__(256) void fused_agg(
    const uint2* __restrict__ entH, const float* __restrict__ usr,
    const float* __restrict__ itc,
    const unsigned long long* __restrict__ pay64, const unsigned int* __restrict__ payu,
    const unsigned int* __restrict__ deg, const unsigned int* __restrict__ offs,
    float* __restrict__ patt, float2* __restrict__ msum,
    float* __restrict__ aggE, float* __restrict__ aggU,
    int nE, int nU, int E, int gAE) {
    __shared__ float4 itcL[8][16];
    int tx = threadIdx.x;
    int bid = blockIdx.x;

    if (bid < gAE) {
        // ---- entity segments: sequential pay64 scores, fp16 row gather (2 lines/row) ----
        int t = bid * 256 + tx;
        int h = t >> 4, l = t & 15;
        if (h >= nE) return;
        unsigned int d = deg[h];
        float m = -3.0e38f, s = 0.f, inv = 0.f;
        float4 acc = make_float4(0.f, 0.f, 0.f, 0.f);
        if (d) {
            unsigned int off = offs[h];
            unsigned long long v0 = pay64[off];
            uint2 b0 = entH[(size_t)(unsigned int)(v0 & 0xffffffffu) * 16 + l];
            for (unsigned int j = 0; j < d; j++) {
                unsigned long long v1 = v0; uint2 b1 = b0;
                if (j + 1 < d) {
                    v1 = pay64[off + j + 1];
                    b1 = entH[(size_t)(unsigned int)(v1 & 0xffffffffu) * 16 + l];
                }
                float sc = __uint_as_float((unsigned int)(v0 >> 32));
                float4 a0 = h4_to_f4(b0);
                float mn = fmaxf(m, sc);
                float scale = __expf(m - mn);
                float w = __expf(sc - mn);
                s = s * scale + w;
                acc.x = acc.x * scale + w * a0.x;
                acc.y = acc.y * scale + w * a0.y;
                acc.z = acc.z * scale + w * a0.z;
                acc.w = acc.w * scale + w * a0.w;
                m = mn; v0 = v1; b0 = b1;
            }
            inv = 1.f / s;
        }
        if (l == 0) msum[h] = make_float2(m, inv);
        acc.x *= inv; acc.y *= inv; acc.z *= inv; acc.w *= inv;
        ((float4*)(aggE + (size_t)h * DIM))[l] = acc;
        return;
    }

    // ---- user segments: fp16 rows (11-bit mantissa: score err ~0.002, safe) ----
    if (tx < 128) itcL[tx >> 4][tx & 15] = ((const float4*)itc)[tx];
    __syncthreads();
    int t = (bid - gAE) * 256 + tx;
    int h = t >> 4, l = t & 15;
    if (h >= nU) return;
    int hs = nE + h;
    unsigned int d = deg[hs];
    float m = -3.0e38f, s = 0.f, inv = 0.f;
    float4 acc = make_float4(0.f, 0.f, 0.f, 0.f);
    float4 ur = ((const float4*)(usr + (size_t)h * DIM))[l];
    if (d) {
        unsigned int off = offs[hs] - (unsigned)E;
        unsigned int v0 = payu[off];
        uint2 b0 = entH[(size_t)(v0 & 0x7ffffffu) * 16 + l];
        for (unsigned int j = 0; j < d; j++) {
            unsigned int v1 = v0; uint2 b1 = b0;
            if (j + 1 < d) {
                v1 = payu[off + j + 1];
                b1 = entH[(size_t)(v1 & 0x7ffffffu) * 16 + l];
            }
            float4 a0 = h4_to_f4(b0);
            float4 c = itcL[v0 >> 27][l];
            float p = a0.x * ur.x * c.x + a0.y * ur.y * c.y
                    + a0.z * ur.z * c.z + a0.w * ur.w * c.w;
            p += __shfl_xor(p, 1);
            p += __shfl_xor(p, 2);
            p += __shfl_xor(p, 4);
            p += __shfl_xor(p, 8);
            if (l == 0) patt[off + j] = p;
            float mn = fmaxf(m, p);
            float scale = __expf(m - mn);
            float w = __expf(p - mn);
            s = s * scale + w;
            acc.x = acc.x * scale + w * a0.x;
            acc.y = acc.y * scale + w * a0.y;
            acc.z = acc.z * scale + w * a0.z;
            acc.w = acc.w * scale + w * a0.w;
            m = mn; v0 = v1; b0 = b1;
        }
        inv = 1.f / s;
    }
    if (l == 0) msum[hs] = make_float2(m, inv);
    acc.x *= inv; acc.y *= inv; acc.z *= inv; acc.w *= inv;
    ((float4*)(aggU + (size_t)h * DIM))[l] = acc;
}

// ---- Epilogue: coalesced per-edge weight writes (sequential score reads) ----
__global__ __launch_bounds__(256) void wout(
    const int* __restrict__ head, const int* __restrict__ uidx,
    const float* __restrict__ e_sc, const float* __restrict__ patt,
    const unsigned char* __restrict__ rank_i,
    const unsigned int* __restrict__ offs, const float2* __restrict__ msum,
    float* __restrict__ w1, float* __restrict__ attw, int E, int I, int nE) {
    int t = blockIdx.x * blockDim.x + threadIdx.x;
    if (t < E) {
        float2 mi = msum[head[t]];
        w1[t] = __expf(e_sc[t] - mi.x) * mi.y;
    } else if (t < E + I) {
        int e = t - E; int u = uidx[e];
        float2 mi = msum[nE + u];
        float sc = patt[offs[nE + u] - (unsigned)E + rank_i[e]];
        attw[e] = __expf(sc - mi.x) * mi.y;
    }
}

extern "C" void kernel_launch(void* const* d_in, const int* in_sizes, int n_in,
                              void* d_out, int out_size, void* d_ws, size_t ws_size,
                              hipStream_t stream) {
    const float* ent  = (const float*)d_in[0];
    const float* usr  = (const float*)d_in[1];
    const float* itc  = (const float*)d_in[2];
    const float* rel  = (const float*)d_in[3];
    const int* eidx   = (const int*)d_in[4];
    const int* etype  = (const int*)d_in[5];
    const int* uidx   = (const int*)d_in[6];
    const int* iidx   = (const int*)d_in[7];
    const int* ttype  = (const int*)d_in[8];

    const int E  = in_sizes[4] / 2;
    const int I  = in_sizes[6];
    const int nE = in_sizes[0] / DIM;
    const int nU = in_sizes[1] / DIM;
    const int* head = eidx;
    const int* tail = eidx + E;
    const int NSEG = nE + nU;
    const int NB = (NSEG + SCAN_B - 1) / SCAN_B;   // <= 1024

    float* out_entity = (float*)d_out;
    float* out_user   = out_entity + (size_t)nE * DIM;
    float* out_attw   = out_user + (size_t)nU * DIM;
    float* out_w1     = out_attw + I;

    // workspace layout (u32 units; alignment by construction)
    unsigned int* deg       = (unsigned int*)d_ws;                 // NSEG
    unsigned int* offs      = deg + NSEG;                          // NSEG
    unsigned int* part      = offs + NSEG;                         // 1024
    unsigned long long* pay64 = (unsigned long long*)(part + 1024); // E u64
    unsigned int* payu      = (unsigned int*)(pay64 + E);          // I
    float* e_sc             = (float*)(payu + I);                  // E
    __hip_bfloat16* M       = (__hip_bfloat16*)(e_sc + E);         // nE*RELS bf16
    uint2* entH             = (uint2*)(M + (size_t)nE * RELS);     // nE*16 uint2 (fp16)
    float2* msum            = (float2*)(entH + (size_t)nE * 16);   // NSEG
    float* patt             = (float*)(msum + NSEG);               // I
    unsigned char* rank_e   = (unsigned char*)(patt + I);          // E bytes
    unsigned char* rank_i   = rank_e + E;                          // I bytes

    hipMemsetAsync(deg, 0, (size_t)NSEG * sizeof(unsigned int), stream);

    const int T = 256;
    const int gM  = (nE + TILE_V - 1) / TILE_V;                    // 3125
    const int gD  = (E + I + T - 1) / T;                           // 7813
    const int NG  = ((gM + 1) / 2 > (gD + 4) / 5) ? (gM + 1) / 2 : (gD + 4) / 5;
    const int gAE = (int)(((size_t)nE * 16 + T - 1) / T);
    const int gAU = (int)(((size_t)nU * 16 + T - 1) / T);

    // A: interleaved build(2/7) + degree(5/7) blocks
    buildM_deg<<<dim3((unsigned)(NG * 7)), T, 0, stream>>>(
        ent, rel, M, entH, head, uidx, deg, rank_e, rank_i, nE, E, I, gM);

    // scans over u32 degrees -> CSR offsets
    scan_partial<<<dim3((unsigned)NB), SCAN_B, 0, stream>>>(deg, part, NSEG);
    scan_block<<<dim3(1), 1024, 0, stream>>>(part, NB);
    scan_final<<<dim3((unsigned)NB), SCAN_B, 0, stream>>>(deg, part, offs, NSEG);

    scatter32<<<dim3((unsigned)gD), T, 0, stream>>>(
        M, head, tail, etype, uidx, iidx, ttype, rank_e, rank_i, offs,
        pay64, payu, e_sc, E, I, nE);

    fused_agg<<<dim3((unsigned)(gAE + gAU)), T, 0, stream>>>(
        entH, usr, itc, pay64, payu, deg, offs, patt, msum,
        out_entity, out_user, nE, nU, E, gAE);

    wout<<<dim3((unsigned)gD), T, 0, stream>>>(
        head, uidx, e_sc, patt, rank_i, offs, msum, out_w1, out_attw, E, I, nE);
}